// Round 10
// baseline (249.613 us; speedup 1.0000x reference)
//
#include <hip/hip_runtime.h>

// ---------------------------------------------------------------------------
// Swin-style windowed MHA block, MI355X/gfx950.
// R10 = R9 fusion with ALL conversions reverted to the R8-proven integer f2b
// (bisect: R9's NaN suspected from v_cvt_pk_bf16_f32 inline asm, which m240
// flags as slower anyway). Single fused kernel: attn + GLU-MLP, y in LDS,
// no y_win HBM round-trip. 768-thread block = 12 waves = 2 windows.
// ---------------------------------------------------------------------------

typedef short          s16x8 __attribute__((ext_vector_type(8)));
typedef unsigned short u16x4 __attribute__((ext_vector_type(4)));
typedef unsigned short u16x8 __attribute__((ext_vector_type(8)));
typedef float          f32x4 __attribute__((ext_vector_type(4)));

#define MFMA(A, B, C) __builtin_amdgcn_mfma_f32_16x16x32_bf16((A), (B), (C), 0, 0, 0)

__device__ __forceinline__ unsigned short f2b(float f) {
  unsigned x = __float_as_uint(f);
  x = (x + 0x7FFFu + ((x >> 16) & 1u)) >> 16;   // RNE
  return (unsigned short)x;
}
__device__ __forceinline__ float b2f(unsigned short u) {
  return __uint_as_float(((unsigned)u) << 16);
}
__device__ __forceinline__ u16x4 pk4(f32x4 v) {
  u16x4 r;
  r[0] = f2b(v[0]); r[1] = f2b(v[1]); r[2] = f2b(v[2]); r[3] = f2b(v[3]);
  return r;
}

// [64][32] tiles (Q,K,P-half,AO): 16B-chunk XOR keyed on (t>>1)&3
__device__ __forceinline__ int swz32(int t, int c) {
  return t * 32 + ((((c >> 3) ^ (t >> 1)) & 3) << 3) + (c & 7);
}
// Vt [32][64]: chunk XOR keyed on (d + (d>>3)) & 7
__device__ __forceinline__ int swzV(int d, int t) {
  return d * 64 + ((((t >> 3) ^ (d + (d >> 3))) & 7) << 3) + (t & 7);
}

#define XSTR   200      // xa/g row stride (elems)
// [64][XSTR] tiles: BIJECTIVE chunk XOR (3-bit key, chunk keeps all bits)
__device__ __forceinline__ int xsw(int t, int c) {
  return t * XSTR + ((((c >> 3) ^ ((t >> 3) & 7))) << 3) + (c & 7);
}

#define WSLOT  37376    // elems/window: xa 12800 + 6 heads * 4096
#define QSCALE 0.17677669529663687f

// workspace element offsets (ushort units unless noted)
#define WOFF_QKV   0
#define WOFF_PROJ  110592
#define WOFF_MLP1  147456
#define WOFF_MLP2  221184
#define WOFF_BIASX_BYTES 516096           // float[4096]

// ---------------------------------------------------------------------------
__global__ void prep_kernel(const float* __restrict__ qkv_w,
                            const float* __restrict__ proj_w,
                            const float* __restrict__ mlp1_w,
                            const float* __restrict__ mlp2_w,
                            const float* __restrict__ bias_table,
                            const int*   __restrict__ rel_index,
                            unsigned short* __restrict__ qkv_wb,
                            unsigned short* __restrict__ proj_wb,
                            unsigned short* __restrict__ mlp1_wb,
                            unsigned short* __restrict__ mlp2_wb,
                            float* __restrict__ biasx) {
  int j = blockIdx.x * 256 + threadIdx.x;   // 1024*256 = 262144 jobs exactly
  if (j < 110592) {
    float v = qkv_w[j];
    if (j < 36864) v *= QSCALE;             // fold 1/sqrt(HD) into Q rows
    qkv_wb[j] = f2b(v);
  } else if (j < 147456) {
    proj_wb[j - 110592] = f2b(proj_w[j - 110592]);
  } else if (j < 221184) {
    mlp1_wb[j - 147456] = f2b(mlp1_w[j - 147456]);
  } else if (j < 258048) {
    mlp2_wb[j - 221184] = f2b(mlp2_w[j - 221184]);
  } else {
    int e = j - 258048;                     // 0..4095
    int l = e >> 6, v = e & 63;
    int tm = v >> 4, tn = (v >> 2) & 3, r = v & 3;
    int q = tn * 16 + (l & 15);
    int k = tm * 16 + (l >> 4) * 4 + r;
    biasx[e] = bias_table[rel_index[q * 64 + k]];
  }
}

// ---------------------------------------------------------------------------
__global__ __launch_bounds__(768, 3) void fused_kernel(
    const float* __restrict__ x,
    const unsigned short* __restrict__ qkv_wb, const float* __restrict__ qkv_b,
    const unsigned short* __restrict__ proj_wb, const float* __restrict__ proj_b,
    const float* __restrict__ biasx,
    const unsigned short* __restrict__ w1b, const float* __restrict__ b1,
    const unsigned short* __restrict__ w2b, const float* __restrict__ b2,
    float* __restrict__ out) {
  __shared__ __align__(16) unsigned short sm[2 * WSLOT];  // 149504 B

  const int tid  = threadIdx.x;
  const int lane = tid & 63;
  const int wv   = tid >> 6;          // 0..11
  const int wid  = (wv >= 6) ? 1 : 0; // window within block
  const int hd   = wv - wid * 6;      // head 0..5
  const int l15  = lane & 15;
  const int lg   = lane >> 4;         // 0..3
  const int pair = ((blockIdx.x & 7) << 7) | (blockIdx.x >> 3);  // XCD swizzle
  const int wins0 = pair * 2;

  const float* xwb[2];
  float* owb[2];
#pragma unroll
  for (int wi = 0; wi < 2; ++wi) {
    const int w = wins0 + wi;
    const size_t off = (size_t)(w >> 8) * 192 * 16384
                     + (size_t)(((w >> 4) & 15) * 8) * 128 + (w & 15) * 8;
    xwb[wi] = x + off;
    owb[wi] = out + off;
  }

  // ---- stage both windows: coalesced 32B global reads, swizzled LDS scatter ----
#pragma unroll
  for (int it = 0; it < 4; ++it) {
    int job = tid + 768 * it;         // 0..3071
    int wi = job / 1536;
    int j = job - wi * 1536;
    int c = j >> 3, i = j & 7;        // channel, spatial-row-group
    const float* src = xwb[wi] + (size_t)c * 16384 + i * 128;
    f32x4 v0 = *(const f32x4*)(src);
    f32x4 v1 = *(const f32x4*)(src + 4);
    unsigned short* dst = &sm[wi * WSLOT + (((c >> 3) ^ i) << 3) + (c & 7)];
    dst[(i * 8 + 0) * XSTR] = f2b(v0[0]); dst[(i * 8 + 1) * XSTR] = f2b(v0[1]);
    dst[(i * 8 + 2) * XSTR] = f2b(v0[2]); dst[(i * 8 + 3) * XSTR] = f2b(v0[3]);
    dst[(i * 8 + 4) * XSTR] = f2b(v1[0]); dst[(i * 8 + 5) * XSTR] = f2b(v1[1]);
    dst[(i * 8 + 6) * XSTR] = f2b(v1[2]); dst[(i * 8 + 7) * XSTR] = f2b(v1[3]);
  }
  __syncthreads();  // B0: both xa visible

  unsigned short* xa = sm + wid * WSLOT;                 // [64][XSTR] xsw
  unsigned short* hb = xa + 12800 + hd * 4096;           // 8KB head region
  unsigned short* R0 = hb;            // Q -> Phalf -> AO (4KB, [64][32] swz32)
  unsigned short* R1 = hb + 2048;     // K -> Vt          (4KB)
  const int oQ = hd * 32;

  // ---------------- QKV: Q^T,K^T = mfma(w, x);  V = mfma(x, w) ----------------
  f32x4 accqT[2][4], acckT[2][4], accv[4][2];
#pragma unroll
  for (int m = 0; m < 2; ++m) {
    f32x4 bq4 = *(const f32x4*)&qkv_b[oQ + m * 16 + lg * 4];
    f32x4 bk4 = *(const f32x4*)&qkv_b[192 + oQ + m * 16 + lg * 4];
#pragma unroll
    for (int tn = 0; tn < 4; ++tn) {
      accqT[m][tn] = bq4 * QSCALE;
      acckT[m][tn] = bk4;
    }
  }
#pragma unroll
  for (int nt = 0; nt < 2; ++nt) {
    const float bv = qkv_b[384 + oQ + nt * 16 + l15];
#pragma unroll
    for (int mt = 0; mt < 4; ++mt) accv[mt][nt] = (f32x4){bv, bv, bv, bv};
  }
#pragma unroll
  for (int ks = 0; ks < 6; ++ks) {
    const int k0 = ks * 32 + lg * 8;
    s16x8 bf[4];
#pragma unroll
    for (int tn = 0; tn < 4; ++tn)
      bf[tn] = *(const s16x8*)&xa[xsw(tn * 16 + l15, k0)];
    s16x8 wq[2], wk[2], wvv[2];
#pragma unroll
    for (int m = 0; m < 2; ++m) {
      wq[m] = *(const s16x8*)&qkv_wb[(size_t)(oQ + m * 16 + l15) * 192 + k0];
      wk[m] = *(const s16x8*)&qkv_wb[(size_t)(192 + oQ + m * 16 + l15) * 192 + k0];
      wvv[m] = *(const s16x8*)&qkv_wb[(size_t)(384 + oQ + m * 16 + l15) * 192 + k0];
    }
#pragma unroll
    for (int m = 0; m < 2; ++m)
#pragma unroll
      for (int tn = 0; tn < 4; ++tn) {
        accqT[m][tn] = MFMA(wq[m], bf[tn], accqT[m][tn]);
        acckT[m][tn] = MFMA(wk[m], bf[tn], acckT[m][tn]);
      }
#pragma unroll
    for (int mt = 0; mt < 4; ++mt)
#pragma unroll
      for (int nt = 0; nt < 2; ++nt)
        accv[mt][nt] = MFMA(bf[mt], wvv[nt], accv[mt][nt]);
  }
  // Q,K stores: C[d][t] regs run along d -> u16x4 into row-major [t][d]
#pragma unroll
  for (int m = 0; m < 2; ++m)
#pragma unroll
    for (int tn = 0; tn < 4; ++tn) {
      const int t = tn * 16 + l15, d0 = m * 16 + lg * 4;
      *(u16x4*)&R0[swz32(t, d0)] = pk4(accqT[m][tn]);
      *(u16x4*)&R1[swz32(t, d0)] = pk4(acckT[m][tn]);
    }
  // V -> bf16 regs (accv dies)
  u16x4 vreg[4][2];
#pragma unroll
  for (int mt = 0; mt < 4; ++mt)
#pragma unroll
    for (int nt = 0; nt < 2; ++nt)
      vreg[mt][nt] = pk4(accv[mt][nt]);

  // ---------------- scores^T = mfma(K, Q) + bias ----------------
  const float* bxp = biasx + lane * 64;
  s16x8 kf[4], qf[4];
#pragma unroll
  for (int tm = 0; tm < 4; ++tm)
    kf[tm] = *(const s16x8*)&R1[swz32(tm * 16 + l15, lg * 8)];
#pragma unroll
  for (int tn = 0; tn < 4; ++tn)
    qf[tn] = *(const s16x8*)&R0[swz32(tn * 16 + l15, lg * 8)];
  // Vt over K (after kf reads; in-wave DS order)
#pragma unroll
  for (int mt = 0; mt < 4; ++mt)
#pragma unroll
    for (int nt = 0; nt < 2; ++nt)
      *(u16x4*)&R1[swzV(nt * 16 + l15, mt * 16 + lg * 4)] = vreg[mt][nt];

  f32x4 sc[4][4];
#pragma unroll
  for (int tm = 0; tm < 4; ++tm)
#pragma unroll
    for (int tn = 0; tn < 4; ++tn) {
      f32x4 bfr = *(const f32x4*)&bxp[tm * 16 + tn * 4];
      sc[tm][tn] = MFMA(kf[tm], qf[tn], bfr);
    }
  // softmax over keys: 16 in-lane + shfl_xor 16,32
#pragma unroll
  for (int tn = 0; tn < 4; ++tn) {
    float mx = sc[0][tn][0];
#pragma unroll
    for (int tm = 0; tm < 4; ++tm)
#pragma unroll
      for (int r = 0; r < 4; ++r) mx = fmaxf(mx, sc[tm][tn][r]);
    mx = fmaxf(mx, __shfl_xor(mx, 16));
    mx = fmaxf(mx, __shfl_xor(mx, 32));
    float sum = 0.f;
#pragma unroll
    for (int tm = 0; tm < 4; ++tm)
#pragma unroll
      for (int r = 0; r < 4; ++r) {
        float e = __expf(sc[tm][tn][r] - mx);
        sc[tm][tn][r] = e;
        sum += e;
      }
    sum += __shfl_xor(sum, 16);
    sum += __shfl_xor(sum, 32);
    const float inv = 1.0f / sum;
#pragma unroll
    for (int tm = 0; tm < 4; ++tm)
#pragma unroll
      for (int r = 0; r < 4; ++r) sc[tm][tn][r] *= inv;
  }

  // ---------------- PV as out^T = mfma(Vt, P), P in 4KB halves ----------------
  f32x4 oT[2][4];
#pragma unroll
  for (int m = 0; m < 2; ++m)
#pragma unroll
    for (int tn = 0; tn < 4; ++tn) oT[m][tn] = (f32x4){0.f, 0.f, 0.f, 0.f};
#pragma unroll
  for (int half = 0; half < 2; ++half) {
#pragma unroll
    for (int tm = 0; tm < 2; ++tm)
#pragma unroll
      for (int tn = 0; tn < 4; ++tn)
        *(u16x4*)&R0[swz32(tn * 16 + l15, tm * 16 + lg * 4)] =
            pk4(sc[half * 2 + tm][tn]);
    s16x8 bp[4], av[2];
#pragma unroll
    for (int tn = 0; tn < 4; ++tn)
      bp[tn] = *(const s16x8*)&R0[swz32(tn * 16 + l15, lg * 8)];
#pragma unroll
    for (int m = 0; m < 2; ++m)
      av[m] = *(const s16x8*)&R1[swzV(m * 16 + l15, half * 32 + lg * 8)];
#pragma unroll
    for (int m = 0; m < 2; ++m)
#pragma unroll
      for (int tn = 0; tn < 4; ++tn)
        oT[m][tn] = MFMA(av[m], bp[tn], oT[m][tn]);
  }
  // AO store: C[d][t] -> u16x4 into [t][d]
#pragma unroll
  for (int m = 0; m < 2; ++m)
#pragma unroll
    for (int tn = 0; tn < 4; ++tn)
      *(u16x4*)&R0[swz32(tn * 16 + l15, m * 16 + lg * 4)] = pk4(oT[m][tn]);
  __syncthreads();  // B2: all heads' AO visible

  // ---------------- proj^T = mfma(Wp, AO) + residual RMW ----------------
  f32x4 pjT[2][4];
#pragma unroll
  for (int m = 0; m < 2; ++m) {
    f32x4 bp4 = *(const f32x4*)&proj_b[oQ + m * 16 + lg * 4];
#pragma unroll
    for (int tn = 0; tn < 4; ++tn) pjT[m][tn] = bp4;
  }
#pragma unroll
  for (int hh = 0; hh < 6; ++hh) {
    const unsigned short* aoh = xa + 12800 + hh * 4096;   // head hh's AO
    s16x8 aa[4];
#pragma unroll
    for (int tn = 0; tn < 4; ++tn)
      aa[tn] = *(const s16x8*)&aoh[swz32(tn * 16 + l15, lg * 8)];
    s16x8 wp[2];
#pragma unroll
    for (int m = 0; m < 2; ++m)
      wp[m] = *(const s16x8*)&proj_wb[(size_t)(oQ + m * 16 + l15) * 192 + hh * 32 + lg * 8];
#pragma unroll
    for (int m = 0; m < 2; ++m)
#pragma unroll
      for (int tn = 0; tn < 4; ++tn)
        pjT[m][tn] = MFMA(wp[m], aa[tn], pjT[m][tn]);
  }
  // y = x + proj: vectorized RMW of wave-private swizzled cells
#pragma unroll
  for (int m = 0; m < 2; ++m)
#pragma unroll
    for (int tn = 0; tn < 4; ++tn) {
      const int t = tn * 16 + l15, o0 = oQ + m * 16 + lg * 4;
      const int ad = xsw(t, o0);
      u16x4 old = *(const u16x4*)&xa[ad];
      f32x4 s;
#pragma unroll
      for (int r = 0; r < 4; ++r) s[r] = pjT[m][tn][r] + b2f(old[r]);
      *(u16x4*)&xa[ad] = pk4(s);
    }
  __syncthreads();  // B3: y complete for both windows

  // ================= fused GLU-MLP (per window, 6 waves) =================
  unsigned short* gb = xa + 12800;    // g/m buffer [64][XSTR] xsw (over heads)

  // ---- GEMM1: g^T = mfma(w1, y); wave hd owns a-cols/b-cols [hd*32,+32) ----
  {
    f32x4 accA[2][4], accB[2][4];
#pragma unroll
    for (int ma = 0; ma < 2; ++ma) {
      f32x4 ba4 = *(const f32x4*)&b1[oQ + ma * 16 + lg * 4];
      f32x4 bb4 = *(const f32x4*)&b1[192 + oQ + ma * 16 + lg * 4];
#pragma unroll
      for (int tn = 0; tn < 4; ++tn) {
        accA[ma][tn] = ba4;
        accB[ma][tn] = bb4;
      }
    }
#pragma unroll
    for (int ks = 0; ks < 6; ++ks) {
      const int k0 = ks * 32 + lg * 8;
      s16x8 bf[4];
#pragma unroll
      for (int tn = 0; tn < 4; ++tn)
        bf[tn] = *(const s16x8*)&xa[xsw(tn * 16 + l15, k0)];
      s16x8 wa[2], wb[2];
#pragma unroll
      for (int ma = 0; ma < 2; ++ma) {
        wa[ma] = *(const s16x8*)&w1b[(size_t)(oQ + ma * 16 + l15) * 192 + k0];
        wb[ma] = *(const s16x8*)&w1b[(size_t)(192 + oQ + ma * 16 + l15) * 192 + k0];
      }
#pragma unroll
      for (int ma = 0; ma < 2; ++ma)
#pragma unroll
        for (int tn = 0; tn < 4; ++tn) {
          accA[ma][tn] = MFMA(wa[ma], bf[tn], accA[ma][tn]);
          accB[ma][tn] = MFMA(wb[ma], bf[tn], accB[ma][tn]);
        }
    }
    // GLU in-register, store g^T fragments as u16x4 into gb[t][col]
#pragma unroll
    for (int ma = 0; ma < 2; ++ma)
#pragma unroll
      for (int tn = 0; tn < 4; ++tn) {
        const int t = tn * 16 + l15, c0 = oQ + ma * 16 + lg * 4;
        f32x4 gv;
#pragma unroll
        for (int r = 0; r < 4; ++r) {
          const float a = accA[ma][tn][r];
          const float bgl = accB[ma][tn][r];
          gv[r] = a * (1.0f / (1.0f + __expf(-bgl)));
        }
        *(u16x4*)&gb[xsw(t, c0)] = pk4(gv);
      }
  }
  __syncthreads();  // B4: g complete for both windows

  // ---- GEMM2: m^T = mfma(w2, g); wave hd owns out-cols [hd*32,+32) ----
  f32x4 macc[2][4];
#pragma unroll
  for (int mo = 0; mo < 2; ++mo) {
    f32x4 b24 = *(const f32x4*)&b2[oQ + mo * 16 + lg * 4];
#pragma unroll
    for (int tn = 0; tn < 4; ++tn) macc[mo][tn] = b24;
  }
#pragma unroll
  for (int ks = 0; ks < 6; ++ks) {
    const int k0 = ks * 32 + lg * 8;
    s16x8 gf[4];
#pragma unroll
    for (int tn = 0; tn < 4; ++tn)
      gf[tn] = *(const s16x8*)&gb[xsw(tn * 16 + l15, k0)];
    s16x8 ww[2];
#pragma unroll
    for (int mo = 0; mo < 2; ++mo)
      ww[mo] = *(const s16x8*)&w2b[(size_t)(oQ + mo * 16 + l15) * 192 + k0];
#pragma unroll
    for (int mo = 0; mo < 2; ++mo)
#pragma unroll
      for (int tn = 0; tn < 4; ++tn)
        macc[mo][tn] = MFMA(ww[mo], gf[tn], macc[mo][tn]);
  }
  __syncthreads();  // B5: all g reads done -> m may overwrite gb
#pragma unroll
  for (int mo = 0; mo < 2; ++mo)
#pragma unroll
    for (int tn = 0; tn < 4; ++tn) {
      const int t = tn * 16 + l15, c0 = oQ + mo * 16 + lg * 4;
      *(u16x4*)&gb[xsw(t, c0)] = pk4(macc[mo][tn]);
    }
  __syncthreads();  // B6: m visible

  // ---- epilogue: out = y + m, BCHW fp32, 32-B runs, both windows ----
#pragma unroll
  for (int it = 0; it < 4; ++it) {
    int job = tid + 768 * it;     // 0..3071 = 2 wi x (c + 192*i)
    int wi = job / 1536;
    int j = job - wi * 1536;
    int i = j / 192;
    int c = j - i * 192;
    const unsigned short* yb = sm + wi * WSLOT;
    const unsigned short* mb = yb + 12800;
    float vals[8];
#pragma unroll
    for (int jj = 0; jj < 8; ++jj) {
      const int t = i * 8 + jj;
      const int ad = xsw(t, c);
      vals[jj] = b2f(yb[ad]) + b2f(mb[ad]);
    }
    float* dst = owb[wi] + (size_t)c * 16384 + i * 128;
    f32x4 o0 = {vals[0], vals[1], vals[2], vals[3]};
    f32x4 o1 = {vals[4], vals[5], vals[6], vals[7]};
    *(f32x4*)dst = o0;
    *(f32x4*)(dst + 4) = o1;
  }
}

// ---------------------------------------------------------------------------
extern "C" void kernel_launch(void* const* d_in, const int* in_sizes, int n_in,
                              void* d_out, int out_size, void* d_ws, size_t ws_size,
                              hipStream_t stream) {
  (void)in_sizes; (void)n_in; (void)out_size; (void)ws_size;
  const float* x          = (const float*)d_in[0];
  const float* qkv_w      = (const float*)d_in[1];
  const float* qkv_b      = (const float*)d_in[2];
  const float* proj_w     = (const float*)d_in[3];
  const float* proj_b     = (const float*)d_in[4];
  const float* mlp1_w     = (const float*)d_in[5];
  const float* mlp1_b     = (const float*)d_in[6];
  const float* mlp2_w     = (const float*)d_in[7];
  const float* mlp2_b     = (const float*)d_in[8];
  const float* bias_table = (const float*)d_in[9];
  const int*   rel_index  = (const int*)d_in[10];
  float* out = (float*)d_out;

  char* ws = (char*)d_ws;
  unsigned short* qkv_wb  = (unsigned short*)ws + WOFF_QKV;
  unsigned short* proj_wb = (unsigned short*)ws + WOFF_PROJ;
  unsigned short* mlp1_wb = (unsigned short*)ws + WOFF_MLP1;
  unsigned short* mlp2_wb = (unsigned short*)ws + WOFF_MLP2;
  float*          biasx   = (float*)(ws + WOFF_BIASX_BYTES);

  hipLaunchKernelGGL(prep_kernel, dim3(1024), dim3(256), 0, stream,
                     qkv_w, proj_w, mlp1_w, mlp2_w, bias_table, rel_index,
                     qkv_wb, proj_wb, mlp1_wb, mlp2_wb, biasx);
  hipLaunchKernelGGL(fused_kernel, dim3(1024), dim3(768), 0, stream,
                     x, qkv_wb, qkv_b, proj_wb, proj_b, biasx,
                     mlp1_wb, mlp1_b, mlp2_wb, mlp2_b, out);
}